// Round 17
// baseline (38.163 us; speedup 1.0000x reference)
//
#include <hip/hip_runtime.h>
#include <stdint.h>

#define NPIX   3136        // 56*56
#define MROWS  12544       // 4*3136
#define SCALE  0.17677669529663687f  // 32^-0.5
#define ASTR   136         // atts row stride (halves): 17 granules, odd
#define HP     140         // halo pixels per fused block (14 x 10)
#define HCH    35          // HP*16/64 staging chunks per buffer

// ws layout (halves)
#define Q_OFF   0u
#define Q_SZ    1605632u           // MROWS*128 (dense q)
#define PADB    3844u              // 62*62 padded pixels per batch
#define PAD_BST 492032u            // PADB*128 halves per batch
#define PAD_SZ  1968128u           // 4*PAD_BST
#define KP_OFF  (Q_OFF + Q_SZ)
#define VP_OFF  (KP_OFF + PAD_SZ)
#define PW_OFF  (VP_OFF + PAD_SZ)  // 128*128 halves

// K/V LDS: row stride exactly 128 halves + R13-validated per-row XOR swizzle.
// Writes: global_load_lds deposits linearly (slot = e&15); the SOURCE granule
// is inverse-permuted (g = slot ^ (p&7)) per rule "both-sides-or-neither".
// Reads: KVIDX retrieves original d (d always a multiple of 8 halves).
// Bank floor check (8x4 tile wave = 16 px x 4 subs): nb = 10*pi+pj+c has
// each residue mod 8 exactly twice -> quad = ((h4+sub)^(nb&7))&7 puts exactly
// 8 lanes/quad.
#define KVIDX(p, d) (((p) << 7) + ((d) ^ (((p) & 7) << 3)))

typedef __attribute__((ext_vector_type(8))) _Float16 half8;
typedef __attribute__((ext_vector_type(2))) _Float16 v2h;
typedef __attribute__((ext_vector_type(4))) float    f32x4;

typedef __attribute__((address_space(3))) void*       as3_void_ptr;
typedef const __attribute__((address_space(1))) void* as1_cvoid_ptr;

// async global->LDS DMA, 16B/lane: dest = wave-uniform lds base + lane*16
__device__ __forceinline__ void gld_lds16(const void* g, void* l) {
    __builtin_amdgcn_global_load_lds((as1_cvoid_ptr)g, (as3_void_ptr)l, 16, 0, 0);
}

#if defined(__has_builtin)
#if __has_builtin(__builtin_amdgcn_fdot2)
#define HAS_FDOT2 1
#endif
#endif

// sum across each aligned quad of 4 lanes via DPP quad_perm
__device__ __forceinline__ float quad_reduce_sum(float x) {
    x += __int_as_float(__builtin_amdgcn_mov_dpp(__float_as_int(x), 0xB1, 0xF, 0xF, true));
    x += __int_as_float(__builtin_amdgcn_mov_dpp(__float_as_int(x), 0x4E, 0xF, 0xF, true));
    return x;
}

// 8-wide fp16 dot with fp32 accumulate (v_dot2_f32_f16 x4)
__device__ __forceinline__ float dot8h(half8 a, half8 b, float acc) {
#ifdef HAS_FDOT2
    union { half8 v; v2h p[4]; } ua, ub;
    ua.v = a; ub.v = b;
    acc = __builtin_amdgcn_fdot2(ua.p[0], ub.p[0], acc, false);
    acc = __builtin_amdgcn_fdot2(ua.p[1], ub.p[1], acc, false);
    acc = __builtin_amdgcn_fdot2(ua.p[2], ub.p[2], acc, false);
    acc = __builtin_amdgcn_fdot2(ua.p[3], ub.p[3], acc, false);
#else
#pragma unroll
    for (int i = 0; i < 8; ++i) acc += (float)a[i] * (float)b[i];
#endif
    return acc;
}

// ---------------------------------------------------------------------------
// QKV GEMM — pinned R11/R14 body (R4 tiles, 2-chunk K-pipeline, XCD-affine
// grid, folded proj_w fp16 conversion). R17 additions:
//  - k/v scatter goes to PADDED [b][62x62][128] buffers (zero border =
//    reference zero-padding), q stays dense.
//  - blocks f<354 zero the pad region (1 half8/thread, disjoint from
//    interior writes; complete before the natten launch by kernel boundary).
// Fragment maps (16x16x32): A: m=l&15, k=(l>>4)*8+i; B mirrored;
// D: col=l&15, row=(l>>4)*4+reg [m89-verified, validated rounds 3-16].
// ---------------------------------------------------------------------------
template<int BM, int BN, int WM, int WN>
__global__ __launch_bounds__(256)
void qkv_mfma(const float* __restrict__ A, const float* __restrict__ W,
              const float* __restrict__ bias, _Float16* __restrict__ qout,
              _Float16* __restrict__ kpad, _Float16* __restrict__ vpad,
              const float* __restrict__ pw, _Float16* __restrict__ pwh)
{
    constexpr int WTM = BM / WM;
    constexpr int WTN = BN / WN;
    constexpr int FM  = WTM / 16;
    constexpr int FN  = WTN / 16;
    constexpr int AIT = BM * 16 / 256;   // float4s per thread per 64-K chunk
    constexpr int WIT = BN * 16 / 256;
    const int t  = threadIdx.x;
    const int f  = blockIdx.x;           // 0..599

    // folded one-time proj_w conversion (128x128 = 4096 float4s)
    if (f < 16) {
        int idx = f * 256 + t;
        float4 v = *reinterpret_cast<const float4*>(pw + (size_t)idx * 4);
        union { _Float16 h[4]; uint2 u; } cv;
        cv.h[0] = (_Float16)v.x; cv.h[1] = (_Float16)v.y;
        cv.h[2] = (_Float16)v.z; cv.h[3] = (_Float16)v.w;
        *reinterpret_cast<uint2*>(pwh + (size_t)idx * 4) = cv.u;
    }

    // zero-fill the 708 pad pixels x 16 granules x 4 batches x 2 buffers
    // (90,624 half8 stores = 354 blocks x 256 threads, exactly)
    if (f < 354) {
        int idx = f * 256 + t;
        int g   = idx & 15;
        int r2  = idx >> 4;              // 0..5663
        int pp  = r2 % 708;
        int q2  = r2 / 708;              // 0..7
        int bz  = q2 & 3;
        _Float16* dstb = (q2 >> 2) ? vpad : kpad;
        int pr, pc;
        if (pp < 186)      { pr = pp / 62; pc = pp - pr * 62; }
        else if (pp < 372) { int j = pp - 186; int jr = j / 62; pr = 59 + jr; pc = j - jr * 62; }
        else               { int j = pp - 372; int jr = j / 6;  pr = 3 + jr;
                             int c6 = j - jr * 6; pc = (c6 < 3) ? c6 : c6 + 56; }
        *reinterpret_cast<half8*>(
            &dstb[((size_t)bz * PADB + pr * 62 + pc) * 128 + g * 8]) =
            (half8){0,0,0,0,0,0,0,0};
    }

    // XCD-affine work assignment: XCD g = f%8 covers batch g/2, half g%2.
    const int g    = f & 7;
    const int w_   = f >> 3;             // 0..74
    const int xi   = w_ / 3;
    const int yc   = w_ % 3;
    const int xhat = (g & 1) ? 25 + xi : xi;
    if (xhat >= ((g & 1) ? 49 : 25)) return;   // 12 idle pad blocks (f>=576)
    const int row0 = ((g >> 1) * 49 + xhat) * BM;
    const int col0 = yc * BN;

    const int w  = t >> 6;
    const int l  = t & 63;
    const int wm = w / WN;
    const int wn = w % WN;

    __shared__ _Float16 Ah[BM * 128];
    __shared__ _Float16 Wh[BN * 128];

    float4 pa[AIT], pwr[WIT];

    // ---- load chunk 0 (k 0..63) into registers ----
#pragma unroll
    for (int it = 0; it < AIT; ++it) {
        int idx = t + it * 256;
        int r = idx >> 4, k0 = (idx & 15) << 2;
        pa[it] = *reinterpret_cast<const float4*>(A + (size_t)(row0 + r) * 128 + k0);
    }
#pragma unroll
    for (int it = 0; it < WIT; ++it) {
        int idx = t + it * 256;
        int r = idx >> 4, k0 = (idx & 15) << 2;
        pwr[it] = *reinterpret_cast<const float4*>(W + (size_t)(col0 + r) * 128 + k0);
    }
    // ---- write chunk 0 to LDS (cvt fp16, swizzled) ----
#pragma unroll
    for (int it = 0; it < AIT; ++it) {
        int idx = t + it * 256;
        int r = idx >> 4, k0 = (idx & 15) << 2;
        union { _Float16 h[4]; uint2 u; } cv;
        cv.h[0] = (_Float16)pa[it].x; cv.h[1] = (_Float16)pa[it].y;
        cv.h[2] = (_Float16)pa[it].z; cv.h[3] = (_Float16)pa[it].w;
        *reinterpret_cast<uint2*>(&Ah[r * 128 + (k0 ^ ((r & 7) << 3))]) = cv.u;
    }
#pragma unroll
    for (int it = 0; it < WIT; ++it) {
        int idx = t + it * 256;
        int r = idx >> 4, k0 = (idx & 15) << 2;
        union { _Float16 h[4]; uint2 u; } cv;
        cv.h[0] = (_Float16)pwr[it].x; cv.h[1] = (_Float16)pwr[it].y;
        cv.h[2] = (_Float16)pwr[it].z; cv.h[3] = (_Float16)pwr[it].w;
        *reinterpret_cast<uint2*>(&Wh[r * 128 + (k0 ^ ((r & 7) << 3))]) = cv.u;
    }
    __syncthreads();                     // bar1: chunk 0 ready

    // ---- issue chunk 1 loads (k 64..127) — fly under chunk-0 MFMAs ----
#pragma unroll
    for (int it = 0; it < AIT; ++it) {
        int idx = t + it * 256;
        int r = idx >> 4, k0 = 64 + ((idx & 15) << 2);
        pa[it] = *reinterpret_cast<const float4*>(A + (size_t)(row0 + r) * 128 + k0);
    }
#pragma unroll
    for (int it = 0; it < WIT; ++it) {
        int idx = t + it * 256;
        int r = idx >> 4, k0 = 64 + ((idx & 15) << 2);
        pwr[it] = *reinterpret_cast<const float4*>(W + (size_t)(col0 + r) * 128 + k0);
    }

    f32x4 acc[FM][FN];
#pragma unroll
    for (int mf = 0; mf < FM; ++mf)
#pragma unroll
        for (int nf = 0; nf < FN; ++nf) acc[mf][nf] = (f32x4){0.f, 0.f, 0.f, 0.f};

    // ---- compute chunk 0 (ks 0,1) ----
#pragma unroll
    for (int ks = 0; ks < 2; ++ks) {
        const int kb = ks * 32 + ((l >> 4) << 3);
        half8 a[FM], b[FN];
#pragma unroll
        for (int mf = 0; mf < FM; ++mf) {
            int m = wm * WTM + mf * 16 + (l & 15);
            a[mf] = *reinterpret_cast<const half8*>(&Ah[m * 128 + (kb ^ ((m & 7) << 3))]);
        }
#pragma unroll
        for (int nf = 0; nf < FN; ++nf) {
            int n = wn * WTN + nf * 16 + (l & 15);
            b[nf] = *reinterpret_cast<const half8*>(&Wh[n * 128 + (kb ^ ((n & 7) << 3))]);
        }
#pragma unroll
        for (int mf = 0; mf < FM; ++mf)
#pragma unroll
            for (int nf = 0; nf < FN; ++nf)
                acc[mf][nf] = __builtin_amdgcn_mfma_f32_16x16x32_f16(
                    a[mf], b[nf], acc[mf][nf], 0, 0, 0);
    }

    // ---- write chunk 1 to LDS (disjoint k-columns; no hazard) ----
#pragma unroll
    for (int it = 0; it < AIT; ++it) {
        int idx = t + it * 256;
        int r = idx >> 4, k0 = 64 + ((idx & 15) << 2);
        union { _Float16 h[4]; uint2 u; } cv;
        cv.h[0] = (_Float16)pa[it].x; cv.h[1] = (_Float16)pa[it].y;
        cv.h[2] = (_Float16)pa[it].z; cv.h[3] = (_Float16)pa[it].w;
        *reinterpret_cast<uint2*>(&Ah[r * 128 + (k0 ^ ((r & 7) << 3))]) = cv.u;
    }
#pragma unroll
    for (int it = 0; it < WIT; ++it) {
        int idx = t + it * 256;
        int r = idx >> 4, k0 = 64 + ((idx & 15) << 2);
        union { _Float16 h[4]; uint2 u; } cv;
        cv.h[0] = (_Float16)pwr[it].x; cv.h[1] = (_Float16)pwr[it].y;
        cv.h[2] = (_Float16)pwr[it].z; cv.h[3] = (_Float16)pwr[it].w;
        *reinterpret_cast<uint2*>(&Wh[r * 128 + (k0 ^ ((r & 7) << 3))]) = cv.u;
    }
    __syncthreads();                     // bar2: chunk 1 ready

    // ---- compute chunk 1 (ks 2,3) ----
#pragma unroll
    for (int ks = 2; ks < 4; ++ks) {
        const int kb = ks * 32 + ((l >> 4) << 3);
        half8 a[FM], b[FN];
#pragma unroll
        for (int mf = 0; mf < FM; ++mf) {
            int m = wm * WTM + mf * 16 + (l & 15);
            a[mf] = *reinterpret_cast<const half8*>(&Ah[m * 128 + (kb ^ ((m & 7) << 3))]);
        }
#pragma unroll
        for (int nf = 0; nf < FN; ++nf) {
            int n = wn * WTN + nf * 16 + (l & 15);
            b[nf] = *reinterpret_cast<const half8*>(&Wh[n * 128 + (kb ^ ((n & 7) << 3))]);
        }
#pragma unroll
        for (int mf = 0; mf < FM; ++mf)
#pragma unroll
            for (int nf = 0; nf < FN; ++nf)
                acc[mf][nf] = __builtin_amdgcn_mfma_f32_16x16x32_f16(
                    a[mf], b[nf], acc[mf][nf], 0, 0, 0);
    }

    // ---- epilogue: q dense, k/v into padded interior ----
#pragma unroll
    for (int mf = 0; mf < FM; ++mf) {
#pragma unroll
        for (int nf = 0; nf < FN; ++nf) {
#pragma unroll
            for (int r = 0; r < 4; ++r) {
                int row = row0 + wm * WTM + mf * 16 + ((l >> 4) << 2) + r;
                int col = col0 + wn * WTN + nf * 16 + (l & 15);
                float val = acc[mf][nf][r] + bias[col];
                int b_  = row / NPIX;
                int pix = row - b_ * NPIX;
                int which = col >> 7;          // 0=q 1=k 2=v
                _Float16 hv = (_Float16)val;
                if (which == 0) {
                    qout[((size_t)b_ * NPIX + pix) * 128 + (col & 127)] = hv;
                } else {
                    int rr = pix / 56, cc = pix - rr * 56;
                    size_t off = ((size_t)b_ * PADB + (rr + 3) * 62 + (cc + 3)) * 128
                               + (col & 127);
                    (which == 1 ? kpad : vpad)[off] = hv;
                }
            }
        }
    }
}

// ---------------------------------------------------------------------------
// Fused neighborhood attention + output projection — R16 structure with
// DMA halo staging. 8x4 px x 4 heads x 4 lanes = 512 thr; grid 392; dyn LDS
// 71,680B (2 x [140][128] halves); atts [32][136] overlays ksm after bar2.
// R17 change: K/V staged via global_load_lds (16B/lane DMA) from the PADDED
// buffers — no bounds checks, no VGPR round-trip, no ds_writes. Source
// granule pre-swizzled (g = slot ^ (p&7)); reads use R13-validated KVIDX;
// bar1's vmcnt(0) drain covers DMA completion. Everything after bar1 is
// numerically identical to R16 (validated 26.9us).
// OOB neighbors are literal zeros in the padded buffers -> logit = bias
// only, kept in softmax (reference zero-pad semantics).
// ---------------------------------------------------------------------------
__global__ __launch_bounds__(512, 4)
void natten_proj_k(const _Float16* __restrict__ qb, const _Float16* __restrict__ kpad,
                   const _Float16* __restrict__ vpad, const float* __restrict__ rpb,
                   const _Float16* __restrict__ pwh, const float* __restrict__ pb,
                   float* __restrict__ out)
{
    extern __shared__ _Float16 smem[];
    _Float16* ksm  = smem;               // [140][128] swizzled
    _Float16* vsm  = smem + HP * 128;    // [140][128] swizzled
    _Float16* atts = smem;               // [32][136]  (overlays ksm after bar2)

    const int flat = blockIdx.x;         // 0..391
    const int rank = (flat & 7) * 49 + (flat >> 3);
    const int tile = rank % 98;
    const int b    = rank / 98;          // 0..3
    const int ti = (tile / 14) * 8;
    const int tj = (tile % 14) * 4;
    const int t   = threadIdx.x;
    const int sub = t & 3;               // d-slice (8 halves) within head
    const int px  = (t >> 2) & 31;       // 0..31 local pixel
    const int pi  = px >> 2;             // 0..7
    const int pj  = px & 3;              // 0..3
    const int h   = t >> 7;              // 0..3 head (wave-uniform)

    const _Float16* kb_ = kpad + (size_t)b * PAD_BST;
    const _Float16* vb_ = vpad + (size_t)b * PAD_BST;

    // ---- q d-slice for this lane (issued first) ----
    const int pix = (ti + pi) * 56 + (tj + pj);
    half8 qv = *reinterpret_cast<const half8*>(
        qb + ((size_t)b * NPIX + pix) * 128 + h * 32 + sub * 8);

    // ---- DMA-stage K and V halo: 35 chunks x 64 lanes x 16B per buffer.
    //      dest linear (slot = e&15); source granule inverse-permuted. ----
    {
        const int wv8  = t >> 6;         // wave id 0..7
        const int lane = t & 63;
        for (int c = wv8; c < HCH; c += 8) {
            int e = c * 64 + lane;
            int p = e >> 4;
            int g = (e & 15) ^ (p & 7);
            int wi = p / 10, wj = p - wi * 10;
            size_t src = ((size_t)((ti + wi) * 62 + (tj + wj))) * 128 + g * 8;
            gld_lds16(kb_ + src, ksm + (size_t)c * 512);
            gld_lds16(vb_ + src, vsm + (size_t)c * 512);
        }
    }

    __syncthreads();                                   // bar1: vmcnt(0) -> K/V ready

    // ---- QK^T + bias ----
    const float* bias = rpb + h * 169;
    const int dl = h * 32 + sub * 8;
    float logits[49];
    float m = -1e30f;
#pragma unroll
    for (int ki = 0; ki < 7; ++ki) {
#pragma unroll
        for (int kj = 0; kj < 7; ++kj) {
            int nb = (pi + ki) * 10 + (pj + kj);
            half8 kk = *reinterpret_cast<const half8*>(&ksm[KVIDX(nb, dl)]);
            float s = dot8h(qv, kk, 0.f);
            s = quad_reduce_sum(s);
            float lg = s * SCALE + bias[(ki + 3) * 13 + (kj + 3)];
            logits[ki * 7 + kj] = lg;
            m = fmaxf(m, lg);
        }
    }

    __syncthreads();                                   // bar2: K region free

    // ---- softmax (redundant per quad lane; cheap) ----
    float sum = 0.f;
#pragma unroll
    for (int n = 0; n < 49; ++n) {
        float e = __expf(logits[n] - m);
        logits[n] = e;
        sum += e;
    }
    float inv = 1.f / sum;

    // ---- P·V (fp32 accum) ----
    float o[8] = {0.f, 0.f, 0.f, 0.f, 0.f, 0.f, 0.f, 0.f};
#pragma unroll
    for (int ki = 0; ki < 7; ++ki) {
#pragma unroll
        for (int kj = 0; kj < 7; ++kj) {
            int nb = (pi + ki) * 10 + (pj + kj);
            half8 vv = *reinterpret_cast<const half8*>(&vsm[KVIDX(nb, dl)]);
            float wgt = logits[ki * 7 + kj];
#pragma unroll
            for (int i = 0; i < 8; ++i)
                o[i] += wgt * (float)vv[i];
        }
    }

    // ---- proj W B-fragments -> registers (issued now; consumed after bar3,
    //      latency hidden under att-write + barrier sync) ----
    const int l   = t & 63;
    const int wv  = t >> 6;           // 0..7
    const int wm  = wv & 1;           // M tile (16 px)
    const int wn  = wv >> 1;          // N tile (32 cols)
    const int kb0 = (l >> 4) << 3;
    half8 wreg[8];
#pragma unroll
    for (int ks = 0; ks < 4; ++ks) {
        const _Float16* wp = pwh + (size_t)(wn * 32 + (l & 15)) * 128 + ks * 32 + kb0;
        wreg[ks]     = *reinterpret_cast<const half8*>(wp);
        wreg[4 + ks] = *reinterpret_cast<const half8*>(wp + 16 * 128);
    }

    // ---- att -> LDS (K region), fp16 ----
    {
        half8 r;
#pragma unroll
        for (int i = 0; i < 8; ++i) r[i] = (_Float16)(o[i] * inv);
        *reinterpret_cast<half8*>(&atts[px * ASTR + dl]) = r;
    }

    __syncthreads();                                   // bar3: att ready

    // ---- projection: out[32px][128] = att @ Wp^T + pb (B from registers) ----
    f32x4 acc0 = (f32x4){0.f, 0.f, 0.f, 0.f};
    f32x4 acc1 = (f32x4){0.f, 0.f, 0.f, 0.f};
#pragma unroll
    for (int ks = 0; ks < 4; ++ks) {
        const int kb = ks * 32 + kb0;
        half8 a = *reinterpret_cast<const half8*>(&atts[(wm * 16 + (l & 15)) * ASTR + kb]);
        acc0 = __builtin_amdgcn_mfma_f32_16x16x32_f16(a, wreg[ks],     acc0, 0, 0, 0);
        acc1 = __builtin_amdgcn_mfma_f32_16x16x32_f16(a, wreg[4 + ks], acc1, 0, 0, 0);
    }

#pragma unroll
    for (int r = 0; r < 4; ++r) {
        int prow = wm * 16 + ((l >> 4) << 2) + r;          // local pixel 0..31
        int gpix = (ti + (prow >> 2)) * 56 + tj + (prow & 3);
        float* dst = out + ((size_t)b * NPIX + gpix) * 128;
        int c0 = wn * 32 + (l & 15);
        dst[c0]      = acc0[r] + pb[c0];
        dst[c0 + 16] = acc1[r] + pb[c0 + 16];
    }
}

// ---------------------------------------------------------------------------
extern "C" void kernel_launch(void* const* d_in, const int* in_sizes, int n_in,
                              void* d_out, int out_size, void* d_ws, size_t ws_size,
                              hipStream_t stream)
{
    const float* x      = (const float*)d_in[0];
    const float* qkv_w  = (const float*)d_in[1];
    const float* qkv_b  = (const float*)d_in[2];
    const float* rpb    = (const float*)d_in[3];
    const float* proj_w = (const float*)d_in[4];
    const float* proj_b = (const float*)d_in[5];
    float* out = (float*)d_out;

    // ws layout (fp16 halves): q dense | k padded | v padded | proj_w fp16
    _Float16* wsbase = (_Float16*)d_ws;
    _Float16* qbuf = wsbase + Q_OFF;
    _Float16* kpad = wsbase + KP_OFF;
    _Float16* vpad = wsbase + VP_OFF;
    _Float16* pwh  = wsbase + PW_OFF;

    // opt-in to 71,680B dynamic LDS (>64KB default cap); host-side, graph-safe
    hipFuncSetAttribute((const void*)natten_proj_k,
                        hipFuncAttributeMaxDynamicSharedMemorySize,
                        2 * HP * 128 * (int)sizeof(_Float16));

    // 1) QKV projection, XCD-affine 600-block grid (12 idle pads);
    //    also zero-fills k/v pad borders and converts proj_w to fp16
    qkv_mfma<64, 128, 2, 2><<<dim3(600), dim3(256), 0, stream>>>(
        x, qkv_w, qkv_b, qbuf, kpad, vpad, proj_w, pwh);

    // 2) fused neighborhood attention + output projection (DMA staging)
    natten_proj_k<<<dim3(392), dim3(512),
                    2 * HP * 128 * sizeof(_Float16), stream>>>(
        qbuf, kpad, vpad, rpb, pwh, proj_b, out);
}

// Round 18
// 26.749 us; speedup vs baseline: 1.4267x; 1.4267x over previous
//
#include <hip/hip_runtime.h>

#define NPIX   3136        // 56*56
#define MROWS  12544       // 4*3136
#define QKV_STRIDE 1605632 // MROWS*128 halves per q/k/v buffer
#define SCALE  0.17677669529663687f  // 32^-0.5
#define KVS    136         // LDS row stride (halves): 17 granules, odd -> even bank spread
#define HP     140         // halo pixels per fused block (14 x 10)

typedef __attribute__((ext_vector_type(8))) _Float16 half8;
typedef __attribute__((ext_vector_type(2))) _Float16 v2h;
typedef __attribute__((ext_vector_type(4))) float    f32x4;

#if defined(__has_builtin)
#if __has_builtin(__builtin_amdgcn_fdot2)
#define HAS_FDOT2 1
#endif
#endif

// sum across each aligned quad of 4 lanes via DPP quad_perm
__device__ __forceinline__ float quad_reduce_sum(float x) {
    x += __int_as_float(__builtin_amdgcn_mov_dpp(__float_as_int(x), 0xB1, 0xF, 0xF, true));
    x += __int_as_float(__builtin_amdgcn_mov_dpp(__float_as_int(x), 0x4E, 0xF, 0xF, true));
    return x;
}

// 8-wide fp16 dot with fp32 accumulate (v_dot2_f32_f16 x4)
__device__ __forceinline__ float dot8h(half8 a, half8 b, float acc) {
#ifdef HAS_FDOT2
    union { half8 v; v2h p[4]; } ua, ub;
    ua.v = a; ub.v = b;
    acc = __builtin_amdgcn_fdot2(ua.p[0], ub.p[0], acc, false);
    acc = __builtin_amdgcn_fdot2(ua.p[1], ub.p[1], acc, false);
    acc = __builtin_amdgcn_fdot2(ua.p[2], ub.p[2], acc, false);
    acc = __builtin_amdgcn_fdot2(ua.p[3], ub.p[3], acc, false);
#else
#pragma unroll
    for (int i = 0; i < 8; ++i) acc += (float)a[i] * (float)b[i];
#endif
    return acc;
}

// ---------------------------------------------------------------------------
// QKV GEMM — FINAL pinned version (R4 tiles + 2-chunk K-pipelined staging +
// XCD-affine grid + folded one-time proj_w fp32->fp16 conversion).
// Validated: R16 = 26.9us total (same source as R14's 30.1 — run noise).
// Rejected alternatives (all measured): LDS-free direct-fragment (R5, +17us),
// smaller tiles (R7, +3us), DMA-staged natten halo (R17, +11us).
// Fragment maps (16x16x32): A: m=l&15, k=(l>>4)*8+i; B mirrored;
// D: col=l&15, row=(l>>4)*4+reg  [m89-verified, validated rounds 3-16].
// Scatter: head-contiguous fp16 [which][b][pix][128].
// ---------------------------------------------------------------------------
template<int BM, int BN, int WM, int WN>
__global__ __launch_bounds__(256)
void qkv_mfma(const float* __restrict__ A, const float* __restrict__ W,
              const float* __restrict__ bias, _Float16* __restrict__ outh,
              const float* __restrict__ pw, _Float16* __restrict__ pwh)
{
    constexpr int WTM = BM / WM;
    constexpr int WTN = BN / WN;
    constexpr int FM  = WTM / 16;
    constexpr int FN  = WTN / 16;
    constexpr int AIT = BM * 16 / 256;   // float4s per thread per 64-K chunk
    constexpr int WIT = BN * 16 / 256;
    const int t  = threadIdx.x;
    const int f  = blockIdx.x;           // 0..599

    // folded one-time proj_w conversion (128x128 = 4096 float4s; f<16 are
    // always valid work blocks)
    if (f < 16) {
        int idx = f * 256 + t;
        float4 v = *reinterpret_cast<const float4*>(pw + (size_t)idx * 4);
        union { _Float16 h[4]; uint2 u; } cv;
        cv.h[0] = (_Float16)v.x; cv.h[1] = (_Float16)v.y;
        cv.h[2] = (_Float16)v.z; cv.h[3] = (_Float16)v.w;
        *reinterpret_cast<uint2*>(pwh + (size_t)idx * 4) = cv.u;
    }

    // XCD-affine work assignment: XCD g = f%8 covers batch g/2, half g%2.
    const int g    = f & 7;
    const int w_   = f >> 3;             // 0..74
    const int xi   = w_ / 3;
    const int yc   = w_ % 3;
    const int xhat = (g & 1) ? 25 + xi : xi;
    if (xhat >= ((g & 1) ? 49 : 25)) return;   // 12 idle pad blocks
    const int row0 = ((g >> 1) * 49 + xhat) * BM;
    const int col0 = yc * BN;

    const int w  = t >> 6;
    const int l  = t & 63;
    const int wm = w / WN;
    const int wn = w % WN;

    __shared__ _Float16 Ah[BM * 128];
    __shared__ _Float16 Wh[BN * 128];

    float4 pa[AIT], pwr[WIT];

    // ---- load chunk 0 (k 0..63) into registers ----
#pragma unroll
    for (int it = 0; it < AIT; ++it) {
        int idx = t + it * 256;
        int r = idx >> 4, k0 = (idx & 15) << 2;
        pa[it] = *reinterpret_cast<const float4*>(A + (size_t)(row0 + r) * 128 + k0);
    }
#pragma unroll
    for (int it = 0; it < WIT; ++it) {
        int idx = t + it * 256;
        int r = idx >> 4, k0 = (idx & 15) << 2;
        pwr[it] = *reinterpret_cast<const float4*>(W + (size_t)(col0 + r) * 128 + k0);
    }
    // ---- write chunk 0 to LDS (cvt fp16, swizzled) ----
#pragma unroll
    for (int it = 0; it < AIT; ++it) {
        int idx = t + it * 256;
        int r = idx >> 4, k0 = (idx & 15) << 2;
        union { _Float16 h[4]; uint2 u; } cv;
        cv.h[0] = (_Float16)pa[it].x; cv.h[1] = (_Float16)pa[it].y;
        cv.h[2] = (_Float16)pa[it].z; cv.h[3] = (_Float16)pa[it].w;
        *reinterpret_cast<uint2*>(&Ah[r * 128 + (k0 ^ ((r & 7) << 3))]) = cv.u;
    }
#pragma unroll
    for (int it = 0; it < WIT; ++it) {
        int idx = t + it * 256;
        int r = idx >> 4, k0 = (idx & 15) << 2;
        union { _Float16 h[4]; uint2 u; } cv;
        cv.h[0] = (_Float16)pwr[it].x; cv.h[1] = (_Float16)pwr[it].y;
        cv.h[2] = (_Float16)pwr[it].z; cv.h[3] = (_Float16)pwr[it].w;
        *reinterpret_cast<uint2*>(&Wh[r * 128 + (k0 ^ ((r & 7) << 3))]) = cv.u;
    }
    __syncthreads();                     // bar1: chunk 0 ready

    // ---- issue chunk 1 loads (k 64..127) — fly under chunk-0 MFMAs ----
#pragma unroll
    for (int it = 0; it < AIT; ++it) {
        int idx = t + it * 256;
        int r = idx >> 4, k0 = 64 + ((idx & 15) << 2);
        pa[it] = *reinterpret_cast<const float4*>(A + (size_t)(row0 + r) * 128 + k0);
    }
#pragma unroll
    for (int it = 0; it < WIT; ++it) {
        int idx = t + it * 256;
        int r = idx >> 4, k0 = 64 + ((idx & 15) << 2);
        pwr[it] = *reinterpret_cast<const float4*>(W + (size_t)(col0 + r) * 128 + k0);
    }

    f32x4 acc[FM][FN];
#pragma unroll
    for (int mf = 0; mf < FM; ++mf)
#pragma unroll
        for (int nf = 0; nf < FN; ++nf) acc[mf][nf] = (f32x4){0.f, 0.f, 0.f, 0.f};

    // ---- compute chunk 0 (ks 0,1) ----
#pragma unroll
    for (int ks = 0; ks < 2; ++ks) {
        const int kb = ks * 32 + ((l >> 4) << 3);
        half8 a[FM], b[FN];
#pragma unroll
        for (int mf = 0; mf < FM; ++mf) {
            int m = wm * WTM + mf * 16 + (l & 15);
            a[mf] = *reinterpret_cast<const half8*>(&Ah[m * 128 + (kb ^ ((m & 7) << 3))]);
        }
#pragma unroll
        for (int nf = 0; nf < FN; ++nf) {
            int n = wn * WTN + nf * 16 + (l & 15);
            b[nf] = *reinterpret_cast<const half8*>(&Wh[n * 128 + (kb ^ ((n & 7) << 3))]);
        }
#pragma unroll
        for (int mf = 0; mf < FM; ++mf)
#pragma unroll
            for (int nf = 0; nf < FN; ++nf)
                acc[mf][nf] = __builtin_amdgcn_mfma_f32_16x16x32_f16(
                    a[mf], b[nf], acc[mf][nf], 0, 0, 0);
    }

    // ---- write chunk 1 to LDS (disjoint k-columns; no hazard) ----
#pragma unroll
    for (int it = 0; it < AIT; ++it) {
        int idx = t + it * 256;
        int r = idx >> 4, k0 = 64 + ((idx & 15) << 2);
        union { _Float16 h[4]; uint2 u; } cv;
        cv.h[0] = (_Float16)pa[it].x; cv.h[1] = (_Float16)pa[it].y;
        cv.h[2] = (_Float16)pa[it].z; cv.h[3] = (_Float16)pa[it].w;
        *reinterpret_cast<uint2*>(&Ah[r * 128 + (k0 ^ ((r & 7) << 3))]) = cv.u;
    }
#pragma unroll
    for (int it = 0; it < WIT; ++it) {
        int idx = t + it * 256;
        int r = idx >> 4, k0 = 64 + ((idx & 15) << 2);
        union { _Float16 h[4]; uint2 u; } cv;
        cv.h[0] = (_Float16)pwr[it].x; cv.h[1] = (_Float16)pwr[it].y;
        cv.h[2] = (_Float16)pwr[it].z; cv.h[3] = (_Float16)pwr[it].w;
        *reinterpret_cast<uint2*>(&Wh[r * 128 + (k0 ^ ((r & 7) << 3))]) = cv.u;
    }
    __syncthreads();                     // bar2: chunk 1 ready

    // ---- compute chunk 1 (ks 2,3) ----
#pragma unroll
    for (int ks = 2; ks < 4; ++ks) {
        const int kb = ks * 32 + ((l >> 4) << 3);
        half8 a[FM], b[FN];
#pragma unroll
        for (int mf = 0; mf < FM; ++mf) {
            int m = wm * WTM + mf * 16 + (l & 15);
            a[mf] = *reinterpret_cast<const half8*>(&Ah[m * 128 + (kb ^ ((m & 7) << 3))]);
        }
#pragma unroll
        for (int nf = 0; nf < FN; ++nf) {
            int n = wn * WTN + nf * 16 + (l & 15);
            b[nf] = *reinterpret_cast<const half8*>(&Wh[n * 128 + (kb ^ ((n & 7) << 3))]);
        }
#pragma unroll
        for (int mf = 0; mf < FM; ++mf)
#pragma unroll
            for (int nf = 0; nf < FN; ++nf)
                acc[mf][nf] = __builtin_amdgcn_mfma_f32_16x16x32_f16(
                    a[mf], b[nf], acc[mf][nf], 0, 0, 0);
    }

    // ---- epilogue ----
#pragma unroll
    for (int mf = 0; mf < FM; ++mf) {
#pragma unroll
        for (int nf = 0; nf < FN; ++nf) {
#pragma unroll
            for (int r = 0; r < 4; ++r) {
                int row = row0 + wm * WTM + mf * 16 + ((l >> 4) << 2) + r;
                int col = col0 + wn * WTN + nf * 16 + (l & 15);
                float val = acc[mf][nf][r] + bias[col];
                int b_  = row / NPIX;
                int pix = row - b_ * NPIX;
                int which = col >> 7;          // 0=q 1=k 2=v
                outh[(size_t)which * QKV_STRIDE +
                     ((size_t)b_ * NPIX + pix) * 128 + (col & 127)] = (_Float16)val;
            }
        }
    }
}

// ---------------------------------------------------------------------------
// Fused neighborhood attention + output projection — FINAL pinned version
// (R11/R14/R16; best measured 26.9us total). 8x4 pixel tile x 4 heads x 4
// lanes = 512 threads; grid 392 blocks (all co-resident at 2/CU); dyn LDS
// 76,160B; stride-136 layout (measured ~0 bank conflicts vs 2.5M for the
// R17 stride-128+XOR variant).
// Rejected redesigns (all measured): 4x4 re-tile (R13, +4us), 8-lane split
// + forced occupancy (R15, +112us scratch spill), V direct-from-global
// (R6, +7us), DMA halo staging (R17, +11us).
// Bijective XCD swizzle: XCD g gets ranks [49g, 49(g+1)) = batch g/2,
// image-half g%2. OOB neighbors zero -> logit = bias only, kept in softmax
// (reference zero-pad semantics).
// ---------------------------------------------------------------------------
__global__ __launch_bounds__(512, 4)
void natten_proj_k(const _Float16* __restrict__ qb, const _Float16* __restrict__ kb,
                   const _Float16* __restrict__ vb, const float* __restrict__ rpb,
                   const _Float16* __restrict__ pwh, const float* __restrict__ pb,
                   float* __restrict__ out)
{
    extern __shared__ _Float16 smem[];
    _Float16* ksm  = smem;               // [140][136]
    _Float16* vsm  = smem + HP * KVS;    // [140][136]
    _Float16* atts = smem;               // [32][136]  (overlays ksm after bar2)

    const int flat = blockIdx.x;         // 0..391
    const int rank = (flat & 7) * 49 + (flat >> 3);
    const int tile = rank % 98;
    const int b    = rank / 98;          // 0..3
    const int ti = (tile / 14) * 8;
    const int tj = (tile % 14) * 4;
    const int t   = threadIdx.x;
    const int sub = t & 3;               // d-slice (8 halves) within head
    const int px  = (t >> 2) & 31;       // 0..31 local pixel
    const int pi  = px >> 2;             // 0..7
    const int pj  = px & 3;              // 0..3
    const int h   = t >> 7;              // 0..3 head (wave-uniform)

    const _Float16* kbase = kb + (size_t)b * NPIX * 128;
    const _Float16* vbase = vb + (size_t)b * NPIX * 128;

    // ---- q d-slice for this lane (issued first) ----
    const int pix = (ti + pi) * 56 + (tj + pj);
    half8 qv = *reinterpret_cast<const half8*>(
        qb + ((size_t)b * NPIX + pix) * 128 + h * 32 + sub * 8);

    // ---- stage K and V halo (all heads), 2240 granules over 512 threads ----
    for (int e = t; e < HP * 16; e += 512) {
        int p = e >> 4, g = e & 15;
        int wi = p / 10, wj = p - wi * 10;
        int gi = ti - 3 + wi, gj = tj - 3 + wj;
        bool ok = ((unsigned)gi < 56u) && ((unsigned)gj < 56u);
        size_t src = ((size_t)(gi * 56 + gj)) * 128 + g * 8;
        half8 kv = (half8){0,0,0,0,0,0,0,0};
        if (ok) kv = *reinterpret_cast<const half8*>(kbase + src);
        *reinterpret_cast<half8*>(&ksm[p * KVS + g * 8]) = kv;
        half8 vv = (half8){0,0,0,0,0,0,0,0};
        if (ok) vv = *reinterpret_cast<const half8*>(vbase + src);
        *reinterpret_cast<half8*>(&vsm[p * KVS + g * 8]) = vv;
    }

    __syncthreads();                                   // bar1: K/V ready

    // ---- QK^T + bias ----
    const float* bias = rpb + h * 169;
    float logits[49];
    float m = -1e30f;
#pragma unroll
    for (int ki = 0; ki < 7; ++ki) {
#pragma unroll
        for (int kj = 0; kj < 7; ++kj) {
            int nb = (pi + ki) * 10 + (pj + kj);
            half8 kk = *reinterpret_cast<const half8*>(&ksm[nb * KVS + h * 32 + sub * 8]);
            float s = dot8h(qv, kk, 0.f);
            s = quad_reduce_sum(s);
            float lg = s * SCALE + bias[(ki + 3) * 13 + (kj + 3)];
            logits[ki * 7 + kj] = lg;
            m = fmaxf(m, lg);
        }
    }

    __syncthreads();                                   // bar2: K region free

    // ---- softmax (redundant per quad lane; cheap) ----
    float sum = 0.f;
#pragma unroll
    for (int n = 0; n < 49; ++n) {
        float e = __expf(logits[n] - m);
        logits[n] = e;
        sum += e;
    }
    float inv = 1.f / sum;

    // ---- P·V (fp32 accum) ----
    float o[8] = {0.f, 0.f, 0.f, 0.f, 0.f, 0.f, 0.f, 0.f};
#pragma unroll
    for (int ki = 0; ki < 7; ++ki) {
#pragma unroll
        for (int kj = 0; kj < 7; ++kj) {
            int nb = (pi + ki) * 10 + (pj + kj);
            half8 vv = *reinterpret_cast<const half8*>(&vsm[nb * KVS + h * 32 + sub * 8]);
            float wgt = logits[ki * 7 + kj];
#pragma unroll
            for (int i = 0; i < 8; ++i)
                o[i] += wgt * (float)vv[i];
        }
    }

    // ---- proj W B-fragments -> registers (issued now; consumed after bar3,
    //      latency hidden under att-write + barrier sync) ----
    const int l   = t & 63;
    const int wv  = t >> 6;           // 0..7
    const int wm  = wv & 1;           // M tile (16 px)
    const int wn  = wv >> 1;          // N tile (32 cols)
    const int kb0 = (l >> 4) << 3;
    half8 wreg[8];
#pragma unroll
    for (int ks = 0; ks < 4; ++ks) {
        const _Float16* wp = pwh + (size_t)(wn * 32 + (l & 15)) * 128 + ks * 32 + kb0;
        wreg[ks]     = *reinterpret_cast<const half8*>(wp);
        wreg[4 + ks] = *reinterpret_cast<const half8*>(wp + 16 * 128);
    }

    // ---- att -> LDS (K region), fp16 ----
    {
        half8 r;
#pragma unroll
        for (int i = 0; i < 8; ++i) r[i] = (_Float16)(o[i] * inv);
        *reinterpret_cast<half8*>(&atts[px * KVS + h * 32 + sub * 8]) = r;
    }

    __syncthreads();                                   // bar3: att ready

    // ---- projection: out[32px][128] = att @ Wp^T + pb (B from registers) ----
    f32x4 acc0 = (f32x4){0.f, 0.f, 0.f, 0.f};
    f32x4 acc1 = (f32x4){0.f, 0.f, 0.f, 0.f};
#pragma unroll
    for (int ks = 0; ks < 4; ++ks) {
        const int kb = ks * 32 + kb0;
        half8 a = *reinterpret_cast<const half8*>(&atts[(wm * 16 + (l & 15)) * KVS + kb]);
        acc0 = __builtin_amdgcn_mfma_f32_16x16x32_f16(a, wreg[ks],     acc0, 0, 0, 0);
        acc1 = __builtin_amdgcn_mfma_f32_16x16x32_f16(a, wreg[4 + ks], acc1, 0, 0, 0);
    }

#pragma unroll
    for (int r = 0; r < 4; ++r) {
        int prow = wm * 16 + ((l >> 4) << 2) + r;          // local pixel 0..31
        int gpix = (ti + (prow >> 2)) * 56 + tj + (prow & 3);
        float* dst = out + ((size_t)b * NPIX + gpix) * 128;
        int c0 = wn * 32 + (l & 15);
        dst[c0]      = acc0[r] + pb[c0];
        dst[c0 + 16] = acc1[r] + pb[c0 + 16];
    }
}

// ---------------------------------------------------------------------------
extern "C" void kernel_launch(void* const* d_in, const int* in_sizes, int n_in,
                              void* d_out, int out_size, void* d_ws, size_t ws_size,
                              hipStream_t stream)
{
    const float* x      = (const float*)d_in[0];
    const float* qkv_w  = (const float*)d_in[1];
    const float* qkv_b  = (const float*)d_in[2];
    const float* rpb    = (const float*)d_in[3];
    const float* proj_w = (const float*)d_in[4];
    const float* proj_b = (const float*)d_in[5];
    float* out = (float*)d_out;

    // ws layout (fp16): q | k | v (3.2 MB each, [b][pix][128]) | proj_w fp16
    _Float16* qbuf = (_Float16*)d_ws;
    _Float16* kbuf = qbuf + (size_t)QKV_STRIDE;
    _Float16* vbuf = kbuf + (size_t)QKV_STRIDE;
    _Float16* pwh  = vbuf + (size_t)QKV_STRIDE;   // 128*128 halves = 32 KB

    // opt-in to 76,160B dynamic LDS (>64KB default cap); host-side, graph-safe
    hipFuncSetAttribute((const void*)natten_proj_k,
                        hipFuncAttributeMaxDynamicSharedMemorySize,
                        2 * HP * KVS * (int)sizeof(_Float16));

    // 1) QKV projection, XCD-affine 600-block grid (12 idle pads)
    qkv_mfma<64, 128, 2, 2><<<dim3(600), dim3(256), 0, stream>>>(
        x, qkv_w, qkv_b, qbuf, proj_w, pwh);

    // 2) fused neighborhood attention + output projection (pinned optimum)
    natten_proj_k<<<dim3(392), dim3(512),
                    2 * HP * KVS * sizeof(_Float16), stream>>>(
        qbuf, kbuf, vbuf, rpb, pwh, proj_b, out);
}